// Round 9
// baseline (131.652 us; speedup 1.0000x reference)
//
#include <hip/hip_runtime.h>
#include <math.h>

typedef unsigned long long u64;

#define NBATCH 2
#define LTOK 196
#define DDIM 768
#define NROWS (NBATCH*LTOK)      // 392
#define NLD (NBATCH*LTOK*DDIM)   // 301056

#define PI_F 3.14159265358979323846f
#define S3 0.86602540378443864676f   // sqrt(3)/2

#define RTILE 14
#define JCH 4
#define JLEN 49
#define NCOMB (NBATCH*14*3*JCH)  // 336 blocks, one tile each
#define GRIDB NROWS              // 392 blocks; <= 512 co-residency slots at 2/CU
#define NGRP 7
#define GSZ 56                   // 7 * 56 == 392

// ---------------------------------------------------------------------------
// Coherence-point accessors: relaxed AGENT-scope atomics -> sc-flagged
// loads/stores that reach the device coherence point (MALL), bypassing the
// non-cross-XCD-coherent L2s. NO fences anywhere (rounds 2/3: per-block
// acquire/release cache-maintenance cost ~0.1-0.6 us each).
// Coalescing rule (round 7): lanes of a wave MUST hit consecutive addresses.
// Latency model (rounds 6-8): ~0.7 us per dependent MALL batch; wall time =
// batches x 0.7 / wave-overlap. Round 9: double-buffer to halve the chain.
// ---------------------------------------------------------------------------
__device__ __forceinline__ float aldf(const float* p) {
  unsigned u = __hip_atomic_load((const unsigned*)p, __ATOMIC_RELAXED,
                                 __HIP_MEMORY_SCOPE_AGENT);
  return __uint_as_float(u);
}
__device__ __forceinline__ void astf(float* p, float v) {
  __hip_atomic_store((unsigned*)p, __float_as_uint(v), __ATOMIC_RELAXED,
                     __HIP_MEMORY_SCOPE_AGENT);
}
__device__ __forceinline__ u64 ald64(const u64* p) {
  return __hip_atomic_load(p, __ATOMIC_RELAXED, __HIP_MEMORY_SCOPE_AGENT);
}
__device__ __forceinline__ void ast64(u64* p, u64 v) {
  __hip_atomic_store(p, v, __ATOMIC_RELAXED, __HIP_MEMORY_SCOPE_AGENT);
}

// Shared-memory union: one allocation reused across phases (max = greedy ~12.6 KB)
union ShMem {
  struct { float re[768]; float im[768]; float2 tw[128]; } fft;            // 7168 B
  struct { double rs[4]; double rq[4]; float mu; float sc; } pat;          // 72 B
  struct { float ui[768]; u64 mask[4]; int last; } sim;                    // ~3.1 KB
  struct { u64 Ml[NROWS*4]; int red[4]; int done; } gr;                    // 12564 B
  struct { u64 mrow[4]; } st;
  struct { float lsr[RTILE][JLEN], lnr[RTILE][JLEN]; } cmb;                // 5488 B
};

// ---------------------------------------------------------------------------
// Fence-free grid barrier (proven rounds 4/6/7/8). __syncthreads() drains
// vmcnt(0) in every wave before s_barrier -> all this block's MALL stores are
// ack'd at arrival. Two-level relaxed counter tree, separate 128-B lines.
// ---------------------------------------------------------------------------
__device__ __forceinline__ void gbar(unsigned* bar, int slot) {
  __syncthreads();
  if (threadIdx.x == 0) {
    unsigned* root = bar + (size_t)(slot * 8) * 32;
    unsigned* grp  = bar + (size_t)(slot * 8 + 1 + (blockIdx.x / GSZ)) * 32;
    if (__hip_atomic_fetch_add(grp, 1u, __ATOMIC_RELAXED,
                               __HIP_MEMORY_SCOPE_AGENT) == GSZ - 1u) {
      __hip_atomic_fetch_add(root, 1u, __ATOMIC_RELAXED,
                             __HIP_MEMORY_SCOPE_AGENT);
    }
    while (__hip_atomic_load(root, __ATOMIC_RELAXED,
                             __HIP_MEMORY_SCOPE_AGENT) < (unsigned)NGRP) {
      __builtin_amdgcn_s_sleep(8);
    }
  }
  __syncthreads();
}

// ---------------------------------------------------------------------------
// FFT768 = 3 x FFT256 (radix-2 DIT, bit-reversed in-place) + radix-3 combine.
// ---------------------------------------------------------------------------
__device__ __forceinline__ void fft_butterfly(float* re, float* im,
                                              const float2* T,
                                              int tau, int s, int half) {
  int sub = tau >> 7;            // 0..2
  int b = tau & 127;
  int j = b & (half - 1);
  int p0 = (sub << 8) + ((b >> (s - 1)) << s) + j;
  int p1 = p0 + half;
  float2 w = T[j << (8 - s)];
  float xr = re[p1], xi = im[p1];
  float tr = w.x * xr - w.y * xi;
  float ti = w.x * xi + w.y * xr;
  float ur = re[p0], ui = im[p0];
  re[p0] = ur + tr; im[p0] = ui + ti;
  re[p1] = ur - tr; im[p1] = ui - ti;
}

__device__ __forceinline__ void fft_stages(float* re, float* im,
                                           const float2* T, int t) {
#pragma unroll
  for (int s = 1; s <= 8; s++) {
    int half = 1 << (s - 1);
    fft_butterfly(re, im, T, t, s, half);
    if (t < 128) fft_butterfly(re, im, T, t + 256, s, half);
    __syncthreads();
  }
}

// ---------------------------------------------------------------------------
// Greedy dedup (faithful sequential loop with done-freeze), run by ONE block.
// ---------------------------------------------------------------------------
__device__ void greedy_block(u64* __restrict__ Mb, ShMem& sh) {
  int t = threadIdx.x;
  for (int w = t; w < NROWS * 4; w += 256) sh.gr.Ml[w] = ald64(&Mb[w]);
  __syncthreads();
  for (int i = 0; i < LTOK - 1; i++) {
    int s = 0;
    for (int w = t; w < NROWS * 4; w += 256) s += __popcll(sh.gr.Ml[w]);
#pragma unroll
    for (int o = 32; o > 0; o >>= 1) s += __shfl_down(s, o);
    if ((t & 63) == 0) sh.gr.red[t >> 6] = s;
    __syncthreads();
    if (t == 0)
      sh.gr.done = ((sh.gr.red[0] + sh.gr.red[1] + sh.gr.red[2] + sh.gr.red[3]) == NROWS) ? 1 : 0;
    __syncthreads();
    if (sh.gr.done) break;
    for (int w = t; w < NROWS * 4; w += 256) {
      int a = w / (LTOK * 4);
      int rem = w - a * (LTOK * 4);
      int r = rem >> 2, wi = rem & 3;
      if (r > i) sh.gr.Ml[w] &= ~sh.gr.Ml[(a * LTOK + i) * 4 + wi];
    }
    __syncthreads();
  }
  for (int w = t; w < NROWS * 4; w += 256) ast64(&Mb[w], sh.gr.Ml[w]);
}

// ---------------------------------------------------------------------------
// Single fused kernel (plain launch, 392 blocks): 5 phases, 4 grid barriers.
// = round-8 structure (best measured: 64.3 us) + two isolated fixes:
//   B: DOUBLE-BUFFERED 32-deep batches (dependent chain 24 -> 12 exposures)
//   A2->F: phre/phim carried in REGISTERS (block-local dataflow; was MALL)
// ---------------------------------------------------------------------------
__global__ __launch_bounds__(256, 2) void mega(
    const float* __restrict__ imgs, const float* __restrict__ x,
    const float* __restrict__ ls, const float* __restrict__ nz,
    float* __restrict__ out,
    float* __restrict__ uT, float* __restrict__ sty,
    float* __restrict__ sstd, float* __restrict__ smsk,
    float* __restrict__ numP, float* __restrict__ denP,
    u64* __restrict__ Mb, unsigned* __restrict__ bar) {
  __shared__ ShMem sh;
  const int t = threadIdx.x;
  const int blk = blockIdx.x;
  const int a = blk / LTOK, i = blk - (blk / LTOK) * LTOK;
  unsigned* ctr = bar + 32 * 32;   // line 32: phase-B last-block counter
  float rpr[3], rpi[3];            // phase (unit complex) of own row, A2 -> F

  // ======================= Phase A1: patchify + standardize -> uT =======================
  {
    int hh = i / 14, ww = i - hh * 14;
    float loc[3];
    double s = 0.0, sq = 0.0;
#pragma unroll
    for (int e = 0; e < 3; e++) {
      int d = t + (e << 8);
      int p = d / 48, r = d - p * 48;
      int q2 = r / 3, c = r - q2 * 3;
      float val = imgs[((size_t)(a * 3 + c) * 224 + (hh * 16 + p)) * 224 + (ww * 16 + q2)];
      loc[e] = val;
      s += (double)val;
      sq += (double)val * (double)val;
    }
#pragma unroll
    for (int o = 32; o > 0; o >>= 1) { s += __shfl_down(s, o); sq += __shfl_down(sq, o); }
    if ((t & 63) == 0) { sh.pat.rs[t >> 6] = s; sh.pat.rq[t >> 6] = sq; }
    __syncthreads();
    if (t == 0) {
      double S = sh.pat.rs[0] + sh.pat.rs[1] + sh.pat.rs[2] + sh.pat.rs[3];
      double Q = sh.pat.rq[0] + sh.pat.rq[1] + sh.pat.rq[2] + sh.pat.rq[3];
      double mean = S / 768.0;
      double ss = Q - S * S / 768.0;
      if (ss < 1e-30) ss = 1e-30;
      sh.pat.mu = (float)mean;
      sh.pat.sc = (float)(1.0 / sqrt(ss));
    }
    __syncthreads();
    float mu = sh.pat.mu, sc = sh.pat.sc;
    int col = a * LTOK + i;
#pragma unroll
    for (int e = 0; e < 3; e++) {
      int d = t + (e << 8);
      astf(&uT[(size_t)d * NROWS + col], (loc[e] - mu) * sc);
    }
  }
  __syncthreads();   // union handoff pat -> fft

  // ======================= Phase A2: forward FFT of x row -> sty, reg-phase =========
  {
    if (t < 128) {
      float sn, cs;
      __sincosf(-2.0f * PI_F * (float)t / 256.0f, &sn, &cs);
      sh.fft.tw[t] = make_float2(cs, sn);
    }
    size_t row = ((size_t)a * (LTOK + 1) + 1 + i) * DDIM;
#pragma unroll
    for (int e = 0; e < 3; e++) {
      int d = t + (e << 8);
      int m = d / 3, r = d - 3 * m;          // decimate n = 3m + r
      int p = (r << 8) + (__brev((unsigned)m) >> 24);
      sh.fft.re[p] = x[row + d];
      sh.fft.im[p] = 0.f;
    }
    __syncthreads();
    fft_stages(sh.fft.re, sh.fft.im, sh.fft.tw, t);
    float a0r = sh.fft.re[t],       a0i = sh.fft.im[t];
    float a1r = sh.fft.re[256 + t], a1i = sh.fft.im[256 + t];
    float a2r = sh.fft.re[512 + t], a2i = sh.fft.im[512 + t];
    float sn, cs;
    __sincosf(-2.0f * PI_F * (float)t / 768.0f, &sn, &cs);
    float2 w1 = make_float2(cs, sn);
    float2 w2 = make_float2(cs * cs - sn * sn, 2.f * cs * sn);
    float b1r = a1r * w1.x - a1i * w1.y, b1i = a1r * w1.y + a1i * w1.x;
    float b2r = a2r * w2.x - a2i * w2.y, b2i = a2r * w2.y + a2i * w2.x;
    float Xr[3], Xi[3];
    Xr[0] = a0r + b1r + b2r;
    Xi[0] = a0i + b1i + b2i;
    Xr[1] = a0r + (-0.5f * b1r + S3 * b1i) + (-0.5f * b2r - S3 * b2i);
    Xi[1] = a0i + (-0.5f * b1i - S3 * b1r) + (-0.5f * b2i + S3 * b2r);
    Xr[2] = a0r + (-0.5f * b1r - S3 * b1i) + (-0.5f * b2r + S3 * b2i);
    Xi[2] = a0i + (-0.5f * b1i + S3 * b1r) + (-0.5f * b2i - S3 * b2r);
    size_t ob = ((size_t)a * LTOK + i) * DDIM + t;
#pragma unroll
    for (int s2 = 0; s2 < 3; s2++) {
      float mag = sqrtf(Xr[s2] * Xr[s2] + Xi[s2] * Xi[s2]);
      astf(&sty[ob + (s2 << 8)], mag);
      if (mag > 0.f) { rpr[s2] = Xr[s2] / mag; rpi[s2] = Xi[s2] / mag; }
      else           { rpr[s2] = 1.f;          rpi[s2] = 0.f;          }
    }
  }
  gbar(bar, 0);

  // ======================= Phase B: Sim (coalesced, double-buffered) + greedy =======
  {
    if (t < 4) sh.sim.mask[t] = 0ull;
    int coli = a * LTOK + i;
#pragma unroll
    for (int e = 0; e < 3; e++) {
      int d = t + (e << 8);
      sh.sim.ui[d] = aldf(&uT[(size_t)d * NROWS + coli]);
    }
    __syncthreads();
    int j = i + t;
    if (j < LTOK) {
      const float* col = uT + (a * LTOK + j);
      float acc0 = 0.f, acc1 = 0.f, acc2 = 0.f, acc3 = 0.f;
      float cva[32], cvb[32];
#pragma unroll
      for (int q = 0; q < 32; q++)                      // prologue: batch 0 in flight
        cva[q] = aldf(col + (size_t)q * NROWS);
      for (int d0 = 0; d0 < 768; d0 += 64) {
#pragma unroll
        for (int q = 0; q < 32; q++)                    // prefetch batch d0+32
          cvb[q] = aldf(col + (size_t)(d0 + 32 + q) * NROWS);
#pragma unroll
        for (int q = 0; q < 32; q += 4) {               // consume batch d0
          acc0 += sh.sim.ui[d0 + q]     * cva[q];
          acc1 += sh.sim.ui[d0 + q + 1] * cva[q + 1];
          acc2 += sh.sim.ui[d0 + q + 2] * cva[q + 2];
          acc3 += sh.sim.ui[d0 + q + 3] * cva[q + 3];
        }
        if (d0 + 64 < 768) {
#pragma unroll
          for (int q = 0; q < 32; q++)                  // prefetch batch d0+64
            cva[q] = aldf(col + (size_t)(d0 + 64 + q) * NROWS);
        }
#pragma unroll
        for (int q = 0; q < 32; q += 4) {               // consume batch d0+32
          acc0 += sh.sim.ui[d0 + 32 + q]     * cvb[q];
          acc1 += sh.sim.ui[d0 + 32 + q + 1] * cvb[q + 1];
          acc2 += sh.sim.ui[d0 + 32 + q + 2] * cvb[q + 2];
          acc3 += sh.sim.ui[d0 + 32 + q + 3] * cvb[q + 3];
        }
      }
      float dot = (acc0 + acc1) + (acc2 + acc3);
      if (dot > 0.3f) atomicOr(&sh.sim.mask[j >> 6], 1ull << (j & 63));
    }
    __syncthreads();
    if (t < 4) ast64(&Mb[((size_t)a * LTOK + i) * 4 + t], sh.sim.mask[t]);
    __syncthreads();   // drains vmcnt in all waves -> Mb row at MALL
    if (t == 0)
      sh.sim.last = (__hip_atomic_fetch_add(ctr, 1u, __ATOMIC_RELAXED,
                                            __HIP_MEMORY_SCOPE_AGENT) == GRIDB - 1u) ? 1 : 0;
    __syncthreads();
    int amlast = sh.sim.last;
    __syncthreads();                 // done reading sh.sim before union reuse
    if (amlast) greedy_block(Mb, sh);
  }
  gbar(bar, 1);

  // ======================= Phase D: masked stats =======================
  {
    float* savg = uT;  // uT reused as s_avg from here on
    if (t < 4) sh.st.mrow[t] = ald64(&Mb[((size_t)a * LTOK + i) * 4 + t]);
    __syncthreads();
    int num = __popcll(sh.st.mrow[0]) + __popcll(sh.st.mrow[1]) +
              __popcll(sh.st.mrow[2]) + __popcll(sh.st.mrow[3]);
    float fnum = fmaxf((float)num, 1e-7f);
    float acc0 = 0.f, acc1 = 0.f, acc2 = 0.f;
    for (int w = 0; w < 4; w++) {
      u64 m = sh.st.mrow[w];
      while (m) {
        int b = __ffsll(m) - 1; m &= (m - 1);
        int jj = (w << 6) + b;
        const float* sr = sty + ((size_t)a * LTOK + jj) * DDIM;
        acc0 += aldf(&sr[t]); acc1 += aldf(&sr[t + 256]); acc2 += aldf(&sr[t + 512]);
      }
    }
    float av0 = acc0 / fnum, av1 = acc1 / fnum, av2 = acc2 / fnum;
    float sq0 = 0.f, sq1 = 0.f, sq2 = 0.f;
    for (int w = 0; w < 4; w++) {
      u64 m = sh.st.mrow[w];
      while (m) {
        int b = __ffsll(m) - 1; m &= (m - 1);
        int jj = (w << 6) + b;
        const float* sr = sty + ((size_t)a * LTOK + jj) * DDIM;
        float e0 = aldf(&sr[t]) - av0, e1 = aldf(&sr[t + 256]) - av1, e2 = aldf(&sr[t + 512]) - av2;
        sq0 += e0 * e0; sq1 += e1 * e1; sq2 += e2 * e2;
      }
    }
    size_t o = ((size_t)a * LTOK + i) * DDIM + t;
    float mk0 = acc0 > 0.f ? 1.f : 0.f;
    float mk1 = acc1 > 0.f ? 1.f : 0.f;
    float mk2 = acc2 > 0.f ? 1.f : 0.f;
    astf(&smsk[o], mk0);           astf(&smsk[o + 256], mk1);           astf(&smsk[o + 512], mk2);
    astf(&savg[o], mk0 * av0);     astf(&savg[o + 256], mk1 * av1);     astf(&savg[o + 512], mk2 * av2);
    astf(&sstd[o], mk0 * sqrtf(sq0 / fnum));
    astf(&sstd[o + 256], mk1 * sqrtf(sq1 / fnum));
    astf(&sstd[o + 512], mk2 * sqrtf(sq2 / fnum));
  }
  gbar(bar, 2);

  // ======================= Phase E: split-K partial combine (RTILE=14) ==========
  if (blk < NCOMB) {
    const float* savg = uT;
    int ea = blk / 168;
    int rem = blk - ea * 168;
    int it = rem / 12;
    int r2 = rem - it * 12;
    int dc = r2 >> 2;
    int jc = r2 & 3;
    int i0 = it * RTILE;
    int j0 = jc * JLEN;
    int d = (dc << 8) + t;
    for (int idx = t; idx < RTILE * JLEN; idx += 256) {
      int ii = idx / JLEN, j = idx - ii * JLEN;
      size_t o = ((size_t)(ea * LTOK + i0 + ii)) * LTOK + j0 + j;
      float l = ls[o];
      sh.cmb.lsr[ii][j] = l;
      sh.cmb.lnr[ii][j] = l * nz[o];
    }
    __syncthreads();
    float nm[RTILE], dn[RTILE];
#pragma unroll
    for (int ii = 0; ii < RTILE; ii++) { nm[ii] = 0.f; dn[ii] = 0.f; }
#pragma unroll 7
    for (int j = 0; j < JLEN; j++) {
      size_t b = ((size_t)(ea * LTOK + j0 + j)) * DDIM + d;
      float sd = aldf(&sstd[b]), sv = aldf(&savg[b]), sm = aldf(&smsk[b]);
#pragma unroll
      for (int ii = 0; ii < RTILE; ii++) {
        nm[ii] += sh.cmb.lnr[ii][j] * sd;
        nm[ii] += sh.cmb.lsr[ii][j] * sv;
        dn[ii] += sh.cmb.lsr[ii][j] * sm;
      }
    }
#pragma unroll
    for (int ii = 0; ii < RTILE; ii++) {
      size_t o = ((size_t)jc * NROWS + (ea * LTOK + i0 + ii)) * DDIM + d;
      astf(&numP[o], nm[ii]);
      astf(&denP[o], dn[ii]);
    }
  }
  gbar(bar, 3);

  // ======================= Phase F: reduce + inverse FFT + cls =======================
  {
    if (blk < NBATCH) {  // blocks 0,1 also copy the cls token row
      size_t b = (size_t)blk * (LTOK + 1) * DDIM;
      out[b + t] = x[b + t];
      out[b + t + 256] = x[b + t + 256];
      out[b + t + 512] = x[b + t + 512];
    }
    if (t < 128) {
      float sn, cs;
      __sincosf(2.0f * PI_F * (float)t / 256.0f, &sn, &cs);
      sh.fft.tw[t] = make_float2(cs, sn);
    }
    size_t rowz = ((size_t)a * LTOK + i) * DDIM;
#pragma unroll
    for (int e = 0; e < 3; e++) {
      int d = t + (e << 8);
      float num = 0.f, den = 0.f;
#pragma unroll
      for (int jc = 0; jc < JCH; jc++) {
        size_t o = (size_t)jc * NROWS * DDIM + rowz + d;
        num += aldf(&numP[o]);
        den += aldf(&denP[o]);
      }
      float mg = num / fmaxf(den, 1e-7f);
      int m = d / 3, r = d - 3 * m;          // decimate k = 3m + r
      int p = (r << 8) + (__brev((unsigned)m) >> 24);
      sh.fft.re[p] = mg * rpr[e];            // phase from registers (A2)
      sh.fft.im[p] = mg * rpi[e];
    }
    __syncthreads();
    fft_stages(sh.fft.re, sh.fft.im, sh.fft.tw, t);
    float a0r = sh.fft.re[t],       a0i = sh.fft.im[t];
    float a1r = sh.fft.re[256 + t], a1i = sh.fft.im[256 + t];
    float a2r = sh.fft.re[512 + t], a2i = sh.fft.im[512 + t];
    float sn, cs;
    __sincosf(2.0f * PI_F * (float)t / 768.0f, &sn, &cs);
    float2 w1 = make_float2(cs, sn);
    float2 w2 = make_float2(cs * cs - sn * sn, 2.f * cs * sn);
    float b1r = a1r * w1.x - a1i * w1.y, b1i = a1r * w1.y + a1i * w1.x;
    float b2r = a2r * w2.x - a2i * w2.y, b2i = a2r * w2.y + a2i * w2.x;
    float Xr[3];
    Xr[0] = a0r + b1r + b2r;
    Xr[1] = a0r + (-0.5f * b1r - S3 * b1i) + (-0.5f * b2r + S3 * b2i);
    Xr[2] = a0r + (-0.5f * b1r + S3 * b1i) + (-0.5f * b2r - S3 * b2i);
    size_t ob = ((size_t)a * (LTOK + 1) + 1 + i) * DDIM + t;
    const float inv = 1.0f / 768.0f;
    out[ob]       = Xr[0] * inv;
    out[ob + 256] = Xr[1] * inv;
    out[ob + 512] = Xr[2] * inv;
  }
}

// ---------------------------------------------------------------------------
extern "C" void kernel_launch(void* const* d_in, const int* in_sizes, int n_in,
                              void* d_out, int out_size, void* d_ws, size_t ws_size,
                              hipStream_t stream) {
  (void)in_sizes; (void)n_in; (void)out_size; (void)ws_size;
  const float* x    = (const float*)d_in[0];   // (2,197,768)
  const float* imgs = (const float*)d_in[1];   // (2,3,224,224)
  const float* ls   = (const float*)d_in[2];   // (2,196,196,1)
  const float* nz   = (const float*)d_in[3];   // (2,196,196,1)
  float* out = (float*)d_out;                  // (2,197,768)

  float* wf   = (float*)d_ws;
  float* uT   = wf;                       // 768 x 392 column-major; reused as s_avg
  float* sty  = wf + (size_t)NLD;
  float* sstd = wf + 4 * (size_t)NLD;     // offsets kept from round 8 layout
  float* smsk = wf + 5 * (size_t)NLD;
  float* numP = wf + 6 * (size_t)NLD;     // 4 x NLD
  float* denP = wf + 10 * (size_t)NLD;    // 4 x NLD
  u64* Mb = (u64*)(wf + 14 * (size_t)NLD);
  unsigned* bar = (unsigned*)(Mb + (size_t)NROWS * 4);  // 33 x 128-B lines

  hipMemsetAsync((void*)bar, 0, 33 * 128, stream);   // zero barrier tree + ctr

  mega<<<GRIDB, 256, 0, stream>>>(imgs, x, ls, nz, out,
                                  uT, sty, sstd, smsk,
                                  numP, denP, Mb, bar);
}

// Round 10
// 125.805 us; speedup vs baseline: 1.0465x; 1.0465x over previous
//
#include <hip/hip_runtime.h>
#include <math.h>

typedef unsigned long long u64;

#define NBATCH 2
#define LTOK 196
#define DDIM 768
#define NROWS (NBATCH*LTOK)      // 392
#define NLD (NBATCH*LTOK*DDIM)   // 301056

#define PI_F 3.14159265358979323846f
#define S3 0.86602540378443864676f   // sqrt(3)/2

#define RTILE 14
#define JCH 4
#define JLEN 49
#define NCOMB (NBATCH*14*3*JCH)  // 336 blocks, one tile each
#define GRIDB NROWS              // 392 blocks; <= 512 co-residency slots at 2/CU
#define NGRP 7
#define GSZ 56                   // 7 * 56 == 392

// ---------------------------------------------------------------------------
// Coherence-point accessors: relaxed AGENT-scope atomics -> sc-flagged
// loads/stores that reach the device coherence point (MALL), bypassing the
// non-cross-XCD-coherent L2s. NO fences anywhere (rounds 2/3: per-block
// acquire/release cache-maintenance cost ~0.1-0.6 us each).
// Coalescing rule (round 7): lanes of a wave MUST hit consecutive addresses.
// Latency model (rounds 6-9): ~0.7 us per dependent MALL batch; wall time =
// batches x 0.7 / wave-overlap. Round 9 lesson: source-level double-buffering
// REGRESSES (compiler recycles the registers and re-serializes) — keep the
// single 32-deep batch form the compiler pipelines well.
// ---------------------------------------------------------------------------
__device__ __forceinline__ float aldf(const float* p) {
  unsigned u = __hip_atomic_load((const unsigned*)p, __ATOMIC_RELAXED,
                                 __HIP_MEMORY_SCOPE_AGENT);
  return __uint_as_float(u);
}
__device__ __forceinline__ void astf(float* p, float v) {
  __hip_atomic_store((unsigned*)p, __float_as_uint(v), __ATOMIC_RELAXED,
                     __HIP_MEMORY_SCOPE_AGENT);
}
__device__ __forceinline__ u64 ald64(const u64* p) {
  return __hip_atomic_load(p, __ATOMIC_RELAXED, __HIP_MEMORY_SCOPE_AGENT);
}
__device__ __forceinline__ void ast64(u64* p, u64 v) {
  __hip_atomic_store(p, v, __ATOMIC_RELAXED, __HIP_MEMORY_SCOPE_AGENT);
}

// Shared-memory union: one allocation reused across phases (max = greedy ~12.6 KB)
union ShMem {
  struct { float re[768]; float im[768]; float2 tw[128]; } fft;            // 7168 B
  struct { double rs[4]; double rq[4]; float mu; float sc; } pat;          // 72 B
  struct { float ui[768]; u64 mask[4]; int last; } sim;                    // ~3.1 KB
  struct { u64 Ml[NROWS*4]; int red[4]; int done; } gr;                    // 12564 B
  struct { u64 mrow[4]; } st;
  struct { float lsr[RTILE][JLEN], lnr[RTILE][JLEN]; } cmb;                // 5488 B
};

// ---------------------------------------------------------------------------
// Fence-free grid barrier (proven rounds 4/6/7/8/9). __syncthreads() drains
// vmcnt(0) in every wave before s_barrier -> all this block's MALL stores are
// ack'd at arrival. Two-level relaxed counter tree, separate 128-B lines.
// ---------------------------------------------------------------------------
__device__ __forceinline__ void gbar(unsigned* bar, int slot) {
  __syncthreads();
  if (threadIdx.x == 0) {
    unsigned* root = bar + (size_t)(slot * 8) * 32;
    unsigned* grp  = bar + (size_t)(slot * 8 + 1 + (blockIdx.x / GSZ)) * 32;
    if (__hip_atomic_fetch_add(grp, 1u, __ATOMIC_RELAXED,
                               __HIP_MEMORY_SCOPE_AGENT) == GSZ - 1u) {
      __hip_atomic_fetch_add(root, 1u, __ATOMIC_RELAXED,
                             __HIP_MEMORY_SCOPE_AGENT);
    }
    while (__hip_atomic_load(root, __ATOMIC_RELAXED,
                             __HIP_MEMORY_SCOPE_AGENT) < (unsigned)NGRP) {
      __builtin_amdgcn_s_sleep(8);
    }
  }
  __syncthreads();
}

// ---------------------------------------------------------------------------
// FFT768 = 3 x FFT256 (radix-2 DIT, bit-reversed in-place) + radix-3 combine.
// ---------------------------------------------------------------------------
__device__ __forceinline__ void fft_butterfly(float* re, float* im,
                                              const float2* T,
                                              int tau, int s, int half) {
  int sub = tau >> 7;            // 0..2
  int b = tau & 127;
  int j = b & (half - 1);
  int p0 = (sub << 8) + ((b >> (s - 1)) << s) + j;
  int p1 = p0 + half;
  float2 w = T[j << (8 - s)];
  float xr = re[p1], xi = im[p1];
  float tr = w.x * xr - w.y * xi;
  float ti = w.x * xi + w.y * xr;
  float ur = re[p0], ui = im[p0];
  re[p0] = ur + tr; im[p0] = ui + ti;
  re[p1] = ur - tr; im[p1] = ui - ti;
}

__device__ __forceinline__ void fft_stages(float* re, float* im,
                                           const float2* T, int t) {
#pragma unroll
  for (int s = 1; s <= 8; s++) {
    int half = 1 << (s - 1);
    fft_butterfly(re, im, T, t, s, half);
    if (t < 128) fft_butterfly(re, im, T, t + 256, s, half);
    __syncthreads();
  }
}

// ---------------------------------------------------------------------------
// Greedy dedup (faithful sequential loop with done-freeze), run by ONE block.
// ---------------------------------------------------------------------------
__device__ void greedy_block(u64* __restrict__ Mb, ShMem& sh) {
  int t = threadIdx.x;
  for (int w = t; w < NROWS * 4; w += 256) sh.gr.Ml[w] = ald64(&Mb[w]);
  __syncthreads();
  for (int i = 0; i < LTOK - 1; i++) {
    int s = 0;
    for (int w = t; w < NROWS * 4; w += 256) s += __popcll(sh.gr.Ml[w]);
#pragma unroll
    for (int o = 32; o > 0; o >>= 1) s += __shfl_down(s, o);
    if ((t & 63) == 0) sh.gr.red[t >> 6] = s;
    __syncthreads();
    if (t == 0)
      sh.gr.done = ((sh.gr.red[0] + sh.gr.red[1] + sh.gr.red[2] + sh.gr.red[3]) == NROWS) ? 1 : 0;
    __syncthreads();
    if (sh.gr.done) break;
    for (int w = t; w < NROWS * 4; w += 256) {
      int a = w / (LTOK * 4);
      int rem = w - a * (LTOK * 4);
      int r = rem >> 2, wi = rem & 3;
      if (r > i) sh.gr.Ml[w] &= ~sh.gr.Ml[(a * LTOK + i) * 4 + wi];
    }
    __syncthreads();
  }
  for (int w = t; w < NROWS * 4; w += 256) ast64(&Mb[w], sh.gr.Ml[w]);
}

// ---------------------------------------------------------------------------
// Single fused kernel (plain launch, 392 blocks): 5 phases, 4 grid barriers.
// = round-8 structure (measured 64.3 us) + round-9's reg-phase carry
//   (measured -2.6 MB FETCH / -2.4 MB WRITE). Round-9's sim double-buffer
//   REVERTED (it regressed: compiler re-serialized, 64.3 -> 72.1).
// ---------------------------------------------------------------------------
__global__ __launch_bounds__(256, 2) void mega(
    const float* __restrict__ imgs, const float* __restrict__ x,
    const float* __restrict__ ls, const float* __restrict__ nz,
    float* __restrict__ out,
    float* __restrict__ uT, float* __restrict__ sty,
    float* __restrict__ sstd, float* __restrict__ smsk,
    float* __restrict__ numP, float* __restrict__ denP,
    u64* __restrict__ Mb, unsigned* __restrict__ bar) {
  __shared__ ShMem sh;
  const int t = threadIdx.x;
  const int blk = blockIdx.x;
  const int a = blk / LTOK, i = blk - (blk / LTOK) * LTOK;
  unsigned* ctr = bar + 32 * 32;   // line 32: phase-B last-block counter
  float rpr[3], rpi[3];            // phase (unit complex) of own row, A2 -> F

  // ======================= Phase A1: patchify + standardize -> uT =======================
  {
    int hh = i / 14, ww = i - hh * 14;
    float loc[3];
    double s = 0.0, sq = 0.0;
#pragma unroll
    for (int e = 0; e < 3; e++) {
      int d = t + (e << 8);
      int p = d / 48, r = d - p * 48;
      int q2 = r / 3, c = r - q2 * 3;
      float val = imgs[((size_t)(a * 3 + c) * 224 + (hh * 16 + p)) * 224 + (ww * 16 + q2)];
      loc[e] = val;
      s += (double)val;
      sq += (double)val * (double)val;
    }
#pragma unroll
    for (int o = 32; o > 0; o >>= 1) { s += __shfl_down(s, o); sq += __shfl_down(sq, o); }
    if ((t & 63) == 0) { sh.pat.rs[t >> 6] = s; sh.pat.rq[t >> 6] = sq; }
    __syncthreads();
    if (t == 0) {
      double S = sh.pat.rs[0] + sh.pat.rs[1] + sh.pat.rs[2] + sh.pat.rs[3];
      double Q = sh.pat.rq[0] + sh.pat.rq[1] + sh.pat.rq[2] + sh.pat.rq[3];
      double mean = S / 768.0;
      double ss = Q - S * S / 768.0;
      if (ss < 1e-30) ss = 1e-30;
      sh.pat.mu = (float)mean;
      sh.pat.sc = (float)(1.0 / sqrt(ss));
    }
    __syncthreads();
    float mu = sh.pat.mu, sc = sh.pat.sc;
    int col = a * LTOK + i;
#pragma unroll
    for (int e = 0; e < 3; e++) {
      int d = t + (e << 8);
      astf(&uT[(size_t)d * NROWS + col], (loc[e] - mu) * sc);
    }
  }
  __syncthreads();   // union handoff pat -> fft

  // ======================= Phase A2: forward FFT of x row -> sty, reg-phase =========
  {
    if (t < 128) {
      float sn, cs;
      __sincosf(-2.0f * PI_F * (float)t / 256.0f, &sn, &cs);
      sh.fft.tw[t] = make_float2(cs, sn);
    }
    size_t row = ((size_t)a * (LTOK + 1) + 1 + i) * DDIM;
#pragma unroll
    for (int e = 0; e < 3; e++) {
      int d = t + (e << 8);
      int m = d / 3, r = d - 3 * m;          // decimate n = 3m + r
      int p = (r << 8) + (__brev((unsigned)m) >> 24);
      sh.fft.re[p] = x[row + d];
      sh.fft.im[p] = 0.f;
    }
    __syncthreads();
    fft_stages(sh.fft.re, sh.fft.im, sh.fft.tw, t);
    float a0r = sh.fft.re[t],       a0i = sh.fft.im[t];
    float a1r = sh.fft.re[256 + t], a1i = sh.fft.im[256 + t];
    float a2r = sh.fft.re[512 + t], a2i = sh.fft.im[512 + t];
    float sn, cs;
    __sincosf(-2.0f * PI_F * (float)t / 768.0f, &sn, &cs);
    float2 w1 = make_float2(cs, sn);
    float2 w2 = make_float2(cs * cs - sn * sn, 2.f * cs * sn);
    float b1r = a1r * w1.x - a1i * w1.y, b1i = a1r * w1.y + a1i * w1.x;
    float b2r = a2r * w2.x - a2i * w2.y, b2i = a2r * w2.y + a2i * w2.x;
    float Xr[3], Xi[3];
    Xr[0] = a0r + b1r + b2r;
    Xi[0] = a0i + b1i + b2i;
    Xr[1] = a0r + (-0.5f * b1r + S3 * b1i) + (-0.5f * b2r - S3 * b2i);
    Xi[1] = a0i + (-0.5f * b1i - S3 * b1r) + (-0.5f * b2i + S3 * b2r);
    Xr[2] = a0r + (-0.5f * b1r - S3 * b1i) + (-0.5f * b2r + S3 * b2i);
    Xi[2] = a0i + (-0.5f * b1i + S3 * b1r) + (-0.5f * b2i - S3 * b2r);
    size_t ob = ((size_t)a * LTOK + i) * DDIM + t;
#pragma unroll
    for (int s2 = 0; s2 < 3; s2++) {
      float mag = sqrtf(Xr[s2] * Xr[s2] + Xi[s2] * Xi[s2]);
      astf(&sty[ob + (s2 << 8)], mag);
      if (mag > 0.f) { rpr[s2] = Xr[s2] / mag; rpi[s2] = Xi[s2] / mag; }
      else           { rpr[s2] = 1.f;          rpi[s2] = 0.f;          }
    }
  }
  gbar(bar, 0);

  // ======================= Phase B: Sim (coalesced col walk, 32-deep) + greedy ======
  {
    if (t < 4) sh.sim.mask[t] = 0ull;
    int coli = a * LTOK + i;
#pragma unroll
    for (int e = 0; e < 3; e++) {
      int d = t + (e << 8);
      sh.sim.ui[d] = aldf(&uT[(size_t)d * NROWS + coli]);
    }
    __syncthreads();
    int j = i + t;
    if (j < LTOK) {
      const float* col = uT + (a * LTOK + j);
      float acc0 = 0.f, acc1 = 0.f, acc2 = 0.f, acc3 = 0.f;
      for (int d0 = 0; d0 < 768; d0 += 32) {
        float cv[32];
#pragma unroll
        for (int q = 0; q < 32; q++)
          cv[q] = aldf(col + (size_t)(d0 + q) * NROWS);   // 32 coalesced loads in flight
#pragma unroll
        for (int q = 0; q < 32; q += 4) {
          acc0 += sh.sim.ui[d0 + q]     * cv[q];
          acc1 += sh.sim.ui[d0 + q + 1] * cv[q + 1];
          acc2 += sh.sim.ui[d0 + q + 2] * cv[q + 2];
          acc3 += sh.sim.ui[d0 + q + 3] * cv[q + 3];
        }
      }
      float dot = (acc0 + acc1) + (acc2 + acc3);
      if (dot > 0.3f) atomicOr(&sh.sim.mask[j >> 6], 1ull << (j & 63));
    }
    __syncthreads();
    if (t < 4) ast64(&Mb[((size_t)a * LTOK + i) * 4 + t], sh.sim.mask[t]);
    __syncthreads();   // drains vmcnt in all waves -> Mb row at MALL
    if (t == 0)
      sh.sim.last = (__hip_atomic_fetch_add(ctr, 1u, __ATOMIC_RELAXED,
                                            __HIP_MEMORY_SCOPE_AGENT) == GRIDB - 1u) ? 1 : 0;
    __syncthreads();
    int amlast = sh.sim.last;
    __syncthreads();                 // done reading sh.sim before union reuse
    if (amlast) greedy_block(Mb, sh);
  }
  gbar(bar, 1);

  // ======================= Phase D: masked stats =======================
  {
    float* savg = uT;  // uT reused as s_avg from here on
    if (t < 4) sh.st.mrow[t] = ald64(&Mb[((size_t)a * LTOK + i) * 4 + t]);
    __syncthreads();
    int num = __popcll(sh.st.mrow[0]) + __popcll(sh.st.mrow[1]) +
              __popcll(sh.st.mrow[2]) + __popcll(sh.st.mrow[3]);
    float fnum = fmaxf((float)num, 1e-7f);
    float acc0 = 0.f, acc1 = 0.f, acc2 = 0.f;
    for (int w = 0; w < 4; w++) {
      u64 m = sh.st.mrow[w];
      while (m) {
        int b = __ffsll(m) - 1; m &= (m - 1);
        int jj = (w << 6) + b;
        const float* sr = sty + ((size_t)a * LTOK + jj) * DDIM;
        acc0 += aldf(&sr[t]); acc1 += aldf(&sr[t + 256]); acc2 += aldf(&sr[t + 512]);
      }
    }
    float av0 = acc0 / fnum, av1 = acc1 / fnum, av2 = acc2 / fnum;
    float sq0 = 0.f, sq1 = 0.f, sq2 = 0.f;
    for (int w = 0; w < 4; w++) {
      u64 m = sh.st.mrow[w];
      while (m) {
        int b = __ffsll(m) - 1; m &= (m - 1);
        int jj = (w << 6) + b;
        const float* sr = sty + ((size_t)a * LTOK + jj) * DDIM;
        float e0 = aldf(&sr[t]) - av0, e1 = aldf(&sr[t + 256]) - av1, e2 = aldf(&sr[t + 512]) - av2;
        sq0 += e0 * e0; sq1 += e1 * e1; sq2 += e2 * e2;
      }
    }
    size_t o = ((size_t)a * LTOK + i) * DDIM + t;
    float mk0 = acc0 > 0.f ? 1.f : 0.f;
    float mk1 = acc1 > 0.f ? 1.f : 0.f;
    float mk2 = acc2 > 0.f ? 1.f : 0.f;
    astf(&smsk[o], mk0);           astf(&smsk[o + 256], mk1);           astf(&smsk[o + 512], mk2);
    astf(&savg[o], mk0 * av0);     astf(&savg[o + 256], mk1 * av1);     astf(&savg[o + 512], mk2 * av2);
    astf(&sstd[o], mk0 * sqrtf(sq0 / fnum));
    astf(&sstd[o + 256], mk1 * sqrtf(sq1 / fnum));
    astf(&sstd[o + 512], mk2 * sqrtf(sq2 / fnum));
  }
  gbar(bar, 2);

  // ======================= Phase E: split-K partial combine (RTILE=14) ==========
  if (blk < NCOMB) {
    const float* savg = uT;
    int ea = blk / 168;
    int rem = blk - ea * 168;
    int it = rem / 12;
    int r2 = rem - it * 12;
    int dc = r2 >> 2;
    int jc = r2 & 3;
    int i0 = it * RTILE;
    int j0 = jc * JLEN;
    int d = (dc << 8) + t;
    for (int idx = t; idx < RTILE * JLEN; idx += 256) {
      int ii = idx / JLEN, j = idx - ii * JLEN;
      size_t o = ((size_t)(ea * LTOK + i0 + ii)) * LTOK + j0 + j;
      float l = ls[o];
      sh.cmb.lsr[ii][j] = l;
      sh.cmb.lnr[ii][j] = l * nz[o];
    }
    __syncthreads();
    float nm[RTILE], dn[RTILE];
#pragma unroll
    for (int ii = 0; ii < RTILE; ii++) { nm[ii] = 0.f; dn[ii] = 0.f; }
#pragma unroll 7
    for (int j = 0; j < JLEN; j++) {
      size_t b = ((size_t)(ea * LTOK + j0 + j)) * DDIM + d;
      float sd = aldf(&sstd[b]), sv = aldf(&savg[b]), sm = aldf(&smsk[b]);
#pragma unroll
      for (int ii = 0; ii < RTILE; ii++) {
        nm[ii] += sh.cmb.lnr[ii][j] * sd;
        nm[ii] += sh.cmb.lsr[ii][j] * sv;
        dn[ii] += sh.cmb.lsr[ii][j] * sm;
      }
    }
#pragma unroll
    for (int ii = 0; ii < RTILE; ii++) {
      size_t o = ((size_t)jc * NROWS + (ea * LTOK + i0 + ii)) * DDIM + d;
      astf(&numP[o], nm[ii]);
      astf(&denP[o], dn[ii]);
    }
  }
  gbar(bar, 3);

  // ======================= Phase F: reduce + inverse FFT + cls =======================
  {
    if (blk < NBATCH) {  // blocks 0,1 also copy the cls token row
      size_t b = (size_t)blk * (LTOK + 1) * DDIM;
      out[b + t] = x[b + t];
      out[b + t + 256] = x[b + t + 256];
      out[b + t + 512] = x[b + t + 512];
    }
    if (t < 128) {
      float sn, cs;
      __sincosf(2.0f * PI_F * (float)t / 256.0f, &sn, &cs);
      sh.fft.tw[t] = make_float2(cs, sn);
    }
    size_t rowz = ((size_t)a * LTOK + i) * DDIM;
#pragma unroll
    for (int e = 0; e < 3; e++) {
      int d = t + (e << 8);
      float num = 0.f, den = 0.f;
#pragma unroll
      for (int jc = 0; jc < JCH; jc++) {
        size_t o = (size_t)jc * NROWS * DDIM + rowz + d;
        num += aldf(&numP[o]);
        den += aldf(&denP[o]);
      }
      float mg = num / fmaxf(den, 1e-7f);
      int m = d / 3, r = d - 3 * m;          // decimate k = 3m + r
      int p = (r << 8) + (__brev((unsigned)m) >> 24);
      sh.fft.re[p] = mg * rpr[e];            // phase from registers (A2)
      sh.fft.im[p] = mg * rpi[e];
    }
    __syncthreads();
    fft_stages(sh.fft.re, sh.fft.im, sh.fft.tw, t);
    float a0r = sh.fft.re[t],       a0i = sh.fft.im[t];
    float a1r = sh.fft.re[256 + t], a1i = sh.fft.im[256 + t];
    float a2r = sh.fft.re[512 + t], a2i = sh.fft.im[512 + t];
    float sn, cs;
    __sincosf(2.0f * PI_F * (float)t / 768.0f, &sn, &cs);
    float2 w1 = make_float2(cs, sn);
    float2 w2 = make_float2(cs * cs - sn * sn, 2.f * cs * sn);
    float b1r = a1r * w1.x - a1i * w1.y, b1i = a1r * w1.y + a1i * w1.x;
    float b2r = a2r * w2.x - a2i * w2.y, b2i = a2r * w2.y + a2i * w2.x;
    float Xr[3];
    Xr[0] = a0r + b1r + b2r;
    Xr[1] = a0r + (-0.5f * b1r - S3 * b1i) + (-0.5f * b2r + S3 * b2i);
    Xr[2] = a0r + (-0.5f * b1r + S3 * b1i) + (-0.5f * b2r - S3 * b2i);
    size_t ob = ((size_t)a * (LTOK + 1) + 1 + i) * DDIM + t;
    const float inv = 1.0f / 768.0f;
    out[ob]       = Xr[0] * inv;
    out[ob + 256] = Xr[1] * inv;
    out[ob + 512] = Xr[2] * inv;
  }
}

// ---------------------------------------------------------------------------
extern "C" void kernel_launch(void* const* d_in, const int* in_sizes, int n_in,
                              void* d_out, int out_size, void* d_ws, size_t ws_size,
                              hipStream_t stream) {
  (void)in_sizes; (void)n_in; (void)out_size; (void)ws_size;
  const float* x    = (const float*)d_in[0];   // (2,197,768)
  const float* imgs = (const float*)d_in[1];   // (2,3,224,224)
  const float* ls   = (const float*)d_in[2];   // (2,196,196,1)
  const float* nz   = (const float*)d_in[3];   // (2,196,196,1)
  float* out = (float*)d_out;                  // (2,197,768)

  float* wf   = (float*)d_ws;
  float* uT   = wf;                       // 768 x 392 column-major; reused as s_avg
  float* sty  = wf + (size_t)NLD;
  float* sstd = wf + 4 * (size_t)NLD;     // offsets kept from round 8 layout
  float* smsk = wf + 5 * (size_t)NLD;
  float* numP = wf + 6 * (size_t)NLD;     // 4 x NLD
  float* denP = wf + 10 * (size_t)NLD;    // 4 x NLD
  u64* Mb = (u64*)(wf + 14 * (size_t)NLD);
  unsigned* bar = (unsigned*)(Mb + (size_t)NROWS * 4);  // 33 x 128-B lines

  hipMemsetAsync((void*)bar, 0, 33 * 128, stream);   // zero barrier tree + ctr

  mega<<<GRIDB, 256, 0, stream>>>(imgs, x, ls, nz, out,
                                  uT, sty, sstd, smsk,
                                  numP, denP, Mb, bar);
}

// Round 11
// 122.140 us; speedup vs baseline: 1.0779x; 1.0300x over previous
//
#include <hip/hip_runtime.h>
#include <math.h>

typedef unsigned long long u64;

#define NBATCH 2
#define LTOK 196
#define DDIM 768
#define NROWS (NBATCH*LTOK)      // 392
#define NLD (NBATCH*LTOK*DDIM)   // 301056

#define PI_F 3.14159265358979323846f
#define S3 0.86602540378443864676f   // sqrt(3)/2

#define RTILE 14
#define JCH 4
#define JLEN 49
#define NCOMB (NBATCH*14*3*JCH)  // 336 blocks, one tile each
#define GRIDB NROWS              // 392 blocks; <= 512 co-residency slots at 2/CU
#define NGRP 7
#define GSZ 56                   // 7 * 56 == 392

// ---------------------------------------------------------------------------
// Coherence-point accessors: relaxed AGENT-scope atomics -> sc-flagged
// loads/stores that reach the device coherence point (MALL), bypassing the
// non-cross-XCD-coherent L2s. NO fences anywhere (rounds 2/3: per-block
// acquire/release cache-maintenance cost ~0.1-0.6 us each).
// Coalescing rule (round 7): lanes of a wave MUST hit consecutive addresses.
// Latency model (rounds 6-10): ~0.7 us per dependent MALL batch; wall time =
// batches x 0.7 / wave-overlap. Round 9/10 lesson: do NOT add register
// liveness across phases or hand-roll double buffering — both perturb the
// compiler's 32-deep load pipelining in sim (VGPR 92->76/96, +3-8 us).
// ---------------------------------------------------------------------------
__device__ __forceinline__ float aldf(const float* p) {
  unsigned u = __hip_atomic_load((const unsigned*)p, __ATOMIC_RELAXED,
                                 __HIP_MEMORY_SCOPE_AGENT);
  return __uint_as_float(u);
}
__device__ __forceinline__ void astf(float* p, float v) {
  __hip_atomic_store((unsigned*)p, __float_as_uint(v), __ATOMIC_RELAXED,
                     __HIP_MEMORY_SCOPE_AGENT);
}
__device__ __forceinline__ u64 ald64(const u64* p) {
  return __hip_atomic_load(p, __ATOMIC_RELAXED, __HIP_MEMORY_SCOPE_AGENT);
}
__device__ __forceinline__ void ast64(u64* p, u64 v) {
  __hip_atomic_store(p, v, __ATOMIC_RELAXED, __HIP_MEMORY_SCOPE_AGENT);
}

// Shared-memory union: one allocation reused across phases (max = greedy ~12.6 KB)
union ShMem {
  struct { float re[768]; float im[768]; float2 tw[128]; } fft;            // 7168 B
  struct { double rs[4]; double rq[4]; float mu; float sc; } pat;          // 72 B
  struct { float ui[768]; u64 mask[4]; int last; } sim;                    // ~3.1 KB
  struct { u64 Ml[NROWS*4]; int red[4]; int done; } gr;                    // 12564 B
  struct { u64 mrow[4]; } st;
  struct { float lsr[RTILE][JLEN], lnr[RTILE][JLEN]; } cmb;                // 5488 B
};

// ---------------------------------------------------------------------------
// Fence-free grid barrier (proven rounds 4/6/7/8/9/10). __syncthreads()
// drains vmcnt(0) in every wave before s_barrier -> all this block's MALL
// stores are ack'd at arrival. Two-level relaxed counter tree.
// ---------------------------------------------------------------------------
__device__ __forceinline__ void gbar(unsigned* bar, int slot) {
  __syncthreads();
  if (threadIdx.x == 0) {
    unsigned* root = bar + (size_t)(slot * 8) * 32;
    unsigned* grp  = bar + (size_t)(slot * 8 + 1 + (blockIdx.x / GSZ)) * 32;
    if (__hip_atomic_fetch_add(grp, 1u, __ATOMIC_RELAXED,
                               __HIP_MEMORY_SCOPE_AGENT) == GSZ - 1u) {
      __hip_atomic_fetch_add(root, 1u, __ATOMIC_RELAXED,
                             __HIP_MEMORY_SCOPE_AGENT);
    }
    while (__hip_atomic_load(root, __ATOMIC_RELAXED,
                             __HIP_MEMORY_SCOPE_AGENT) < (unsigned)NGRP) {
      __builtin_amdgcn_s_sleep(8);
    }
  }
  __syncthreads();
}

// ---------------------------------------------------------------------------
// FFT768 = 3 x FFT256 (radix-2 DIT, bit-reversed in-place) + radix-3 combine.
// ---------------------------------------------------------------------------
__device__ __forceinline__ void fft_butterfly(float* re, float* im,
                                              const float2* T,
                                              int tau, int s, int half) {
  int sub = tau >> 7;            // 0..2
  int b = tau & 127;
  int j = b & (half - 1);
  int p0 = (sub << 8) + ((b >> (s - 1)) << s) + j;
  int p1 = p0 + half;
  float2 w = T[j << (8 - s)];
  float xr = re[p1], xi = im[p1];
  float tr = w.x * xr - w.y * xi;
  float ti = w.x * xi + w.y * xr;
  float ur = re[p0], ui = im[p0];
  re[p0] = ur + tr; im[p0] = ui + ti;
  re[p1] = ur - tr; im[p1] = ui - ti;
}

__device__ __forceinline__ void fft_stages(float* re, float* im,
                                           const float2* T, int t) {
#pragma unroll
  for (int s = 1; s <= 8; s++) {
    int half = 1 << (s - 1);
    fft_butterfly(re, im, T, t, s, half);
    if (t < 128) fft_butterfly(re, im, T, t + 256, s, half);
    __syncthreads();
  }
}

// ---------------------------------------------------------------------------
// Greedy dedup (faithful sequential loop with done-freeze), run by ONE block.
// ---------------------------------------------------------------------------
__device__ void greedy_block(u64* __restrict__ Mb, ShMem& sh) {
  int t = threadIdx.x;
  for (int w = t; w < NROWS * 4; w += 256) sh.gr.Ml[w] = ald64(&Mb[w]);
  __syncthreads();
  for (int i = 0; i < LTOK - 1; i++) {
    int s = 0;
    for (int w = t; w < NROWS * 4; w += 256) s += __popcll(sh.gr.Ml[w]);
#pragma unroll
    for (int o = 32; o > 0; o >>= 1) s += __shfl_down(s, o);
    if ((t & 63) == 0) sh.gr.red[t >> 6] = s;
    __syncthreads();
    if (t == 0)
      sh.gr.done = ((sh.gr.red[0] + sh.gr.red[1] + sh.gr.red[2] + sh.gr.red[3]) == NROWS) ? 1 : 0;
    __syncthreads();
    if (sh.gr.done) break;
    for (int w = t; w < NROWS * 4; w += 256) {
      int a = w / (LTOK * 4);
      int rem = w - a * (LTOK * 4);
      int r = rem >> 2, wi = rem & 3;
      if (r > i) sh.gr.Ml[w] &= ~sh.gr.Ml[(a * LTOK + i) * 4 + wi];
    }
    __syncthreads();
  }
  for (int w = t; w < NROWS * 4; w += 256) ast64(&Mb[w], sh.gr.Ml[w]);
}

// ---------------------------------------------------------------------------
// Single fused kernel (plain launch, 392 blocks): 5 phases, 4 grid barriers.
// = round-8 structure (measured 64.3 us) + phase carry A2->F in a DEDICATED
//   LDS slab (shph) — keeps the -5 MB MALL traffic win of the reg-carry
//   WITHOUT the cross-phase register liveness that broke sim codegen in r10.
// ---------------------------------------------------------------------------
__global__ __launch_bounds__(256, 2) void mega(
    const float* __restrict__ imgs, const float* __restrict__ x,
    const float* __restrict__ ls, const float* __restrict__ nz,
    float* __restrict__ out,
    float* __restrict__ uT, float* __restrict__ sty,
    float* __restrict__ sstd, float* __restrict__ smsk,
    float* __restrict__ numP, float* __restrict__ denP,
    u64* __restrict__ Mb, unsigned* __restrict__ bar) {
  __shared__ ShMem sh;
  __shared__ float shph[6][256];   // persistent A2->F phase carry (6 KB, outside union)
  const int t = threadIdx.x;
  const int blk = blockIdx.x;
  const int a = blk / LTOK, i = blk - (blk / LTOK) * LTOK;
  unsigned* ctr = bar + 32 * 32;   // line 32: phase-B last-block counter

  // ======================= Phase A1: patchify + standardize -> uT =======================
  {
    int hh = i / 14, ww = i - hh * 14;
    float loc[3];
    double s = 0.0, sq = 0.0;
#pragma unroll
    for (int e = 0; e < 3; e++) {
      int d = t + (e << 8);
      int p = d / 48, r = d - p * 48;
      int q2 = r / 3, c = r - q2 * 3;
      float val = imgs[((size_t)(a * 3 + c) * 224 + (hh * 16 + p)) * 224 + (ww * 16 + q2)];
      loc[e] = val;
      s += (double)val;
      sq += (double)val * (double)val;
    }
#pragma unroll
    for (int o = 32; o > 0; o >>= 1) { s += __shfl_down(s, o); sq += __shfl_down(sq, o); }
    if ((t & 63) == 0) { sh.pat.rs[t >> 6] = s; sh.pat.rq[t >> 6] = sq; }
    __syncthreads();
    if (t == 0) {
      double S = sh.pat.rs[0] + sh.pat.rs[1] + sh.pat.rs[2] + sh.pat.rs[3];
      double Q = sh.pat.rq[0] + sh.pat.rq[1] + sh.pat.rq[2] + sh.pat.rq[3];
      double mean = S / 768.0;
      double ss = Q - S * S / 768.0;
      if (ss < 1e-30) ss = 1e-30;
      sh.pat.mu = (float)mean;
      sh.pat.sc = (float)(1.0 / sqrt(ss));
    }
    __syncthreads();
    float mu = sh.pat.mu, sc = sh.pat.sc;
    int col = a * LTOK + i;
#pragma unroll
    for (int e = 0; e < 3; e++) {
      int d = t + (e << 8);
      astf(&uT[(size_t)d * NROWS + col], (loc[e] - mu) * sc);
    }
  }
  __syncthreads();   // union handoff pat -> fft

  // ======================= Phase A2: forward FFT of x row -> sty, LDS-phase =========
  {
    if (t < 128) {
      float sn, cs;
      __sincosf(-2.0f * PI_F * (float)t / 256.0f, &sn, &cs);
      sh.fft.tw[t] = make_float2(cs, sn);
    }
    size_t row = ((size_t)a * (LTOK + 1) + 1 + i) * DDIM;
#pragma unroll
    for (int e = 0; e < 3; e++) {
      int d = t + (e << 8);
      int m = d / 3, r = d - 3 * m;          // decimate n = 3m + r
      int p = (r << 8) + (__brev((unsigned)m) >> 24);
      sh.fft.re[p] = x[row + d];
      sh.fft.im[p] = 0.f;
    }
    __syncthreads();
    fft_stages(sh.fft.re, sh.fft.im, sh.fft.tw, t);
    float a0r = sh.fft.re[t],       a0i = sh.fft.im[t];
    float a1r = sh.fft.re[256 + t], a1i = sh.fft.im[256 + t];
    float a2r = sh.fft.re[512 + t], a2i = sh.fft.im[512 + t];
    float sn, cs;
    __sincosf(-2.0f * PI_F * (float)t / 768.0f, &sn, &cs);
    float2 w1 = make_float2(cs, sn);
    float2 w2 = make_float2(cs * cs - sn * sn, 2.f * cs * sn);
    float b1r = a1r * w1.x - a1i * w1.y, b1i = a1r * w1.y + a1i * w1.x;
    float b2r = a2r * w2.x - a2i * w2.y, b2i = a2r * w2.y + a2i * w2.x;
    float Xr[3], Xi[3];
    Xr[0] = a0r + b1r + b2r;
    Xi[0] = a0i + b1i + b2i;
    Xr[1] = a0r + (-0.5f * b1r + S3 * b1i) + (-0.5f * b2r - S3 * b2i);
    Xi[1] = a0i + (-0.5f * b1i - S3 * b1r) + (-0.5f * b2i + S3 * b2r);
    Xr[2] = a0r + (-0.5f * b1r - S3 * b1i) + (-0.5f * b2r + S3 * b2i);
    Xi[2] = a0i + (-0.5f * b1i + S3 * b1r) + (-0.5f * b2i - S3 * b2r);
    size_t ob = ((size_t)a * LTOK + i) * DDIM + t;
#pragma unroll
    for (int s2 = 0; s2 < 3; s2++) {
      float mag = sqrtf(Xr[s2] * Xr[s2] + Xi[s2] * Xi[s2]);
      astf(&sty[ob + (s2 << 8)], mag);
      if (mag > 0.f) { shph[s2][t] = Xr[s2] / mag; shph[3 + s2][t] = Xi[s2] / mag; }
      else           { shph[s2][t] = 1.f;          shph[3 + s2][t] = 0.f;          }
    }
  }
  gbar(bar, 0);

  // ======================= Phase B: Sim (coalesced col walk, 32-deep) + greedy ======
  {
    if (t < 4) sh.sim.mask[t] = 0ull;
    int coli = a * LTOK + i;
#pragma unroll
    for (int e = 0; e < 3; e++) {
      int d = t + (e << 8);
      sh.sim.ui[d] = aldf(&uT[(size_t)d * NROWS + coli]);
    }
    __syncthreads();
    int j = i + t;
    if (j < LTOK) {
      const float* col = uT + (a * LTOK + j);
      float acc0 = 0.f, acc1 = 0.f, acc2 = 0.f, acc3 = 0.f;
      for (int d0 = 0; d0 < 768; d0 += 32) {
        float cv[32];
#pragma unroll
        for (int q = 0; q < 32; q++)
          cv[q] = aldf(col + (size_t)(d0 + q) * NROWS);   // 32 coalesced loads in flight
#pragma unroll
        for (int q = 0; q < 32; q += 4) {
          acc0 += sh.sim.ui[d0 + q]     * cv[q];
          acc1 += sh.sim.ui[d0 + q + 1] * cv[q + 1];
          acc2 += sh.sim.ui[d0 + q + 2] * cv[q + 2];
          acc3 += sh.sim.ui[d0 + q + 3] * cv[q + 3];
        }
      }
      float dot = (acc0 + acc1) + (acc2 + acc3);
      if (dot > 0.3f) atomicOr(&sh.sim.mask[j >> 6], 1ull << (j & 63));
    }
    __syncthreads();
    if (t < 4) ast64(&Mb[((size_t)a * LTOK + i) * 4 + t], sh.sim.mask[t]);
    __syncthreads();   // drains vmcnt in all waves -> Mb row at MALL
    if (t == 0)
      sh.sim.last = (__hip_atomic_fetch_add(ctr, 1u, __ATOMIC_RELAXED,
                                            __HIP_MEMORY_SCOPE_AGENT) == GRIDB - 1u) ? 1 : 0;
    __syncthreads();
    int amlast = sh.sim.last;
    __syncthreads();                 // done reading sh.sim before union reuse
    if (amlast) greedy_block(Mb, sh);
  }
  gbar(bar, 1);

  // ======================= Phase D: masked stats =======================
  {
    float* savg = uT;  // uT reused as s_avg from here on
    if (t < 4) sh.st.mrow[t] = ald64(&Mb[((size_t)a * LTOK + i) * 4 + t]);
    __syncthreads();
    int num = __popcll(sh.st.mrow[0]) + __popcll(sh.st.mrow[1]) +
              __popcll(sh.st.mrow[2]) + __popcll(sh.st.mrow[3]);
    float fnum = fmaxf((float)num, 1e-7f);
    float acc0 = 0.f, acc1 = 0.f, acc2 = 0.f;
    for (int w = 0; w < 4; w++) {
      u64 m = sh.st.mrow[w];
      while (m) {
        int b = __ffsll(m) - 1; m &= (m - 1);
        int jj = (w << 6) + b;
        const float* sr = sty + ((size_t)a * LTOK + jj) * DDIM;
        acc0 += aldf(&sr[t]); acc1 += aldf(&sr[t + 256]); acc2 += aldf(&sr[t + 512]);
      }
    }
    float av0 = acc0 / fnum, av1 = acc1 / fnum, av2 = acc2 / fnum;
    float sq0 = 0.f, sq1 = 0.f, sq2 = 0.f;
    for (int w = 0; w < 4; w++) {
      u64 m = sh.st.mrow[w];
      while (m) {
        int b = __ffsll(m) - 1; m &= (m - 1);
        int jj = (w << 6) + b;
        const float* sr = sty + ((size_t)a * LTOK + jj) * DDIM;
        float e0 = aldf(&sr[t]) - av0, e1 = aldf(&sr[t + 256]) - av1, e2 = aldf(&sr[t + 512]) - av2;
        sq0 += e0 * e0; sq1 += e1 * e1; sq2 += e2 * e2;
      }
    }
    size_t o = ((size_t)a * LTOK + i) * DDIM + t;
    float mk0 = acc0 > 0.f ? 1.f : 0.f;
    float mk1 = acc1 > 0.f ? 1.f : 0.f;
    float mk2 = acc2 > 0.f ? 1.f : 0.f;
    astf(&smsk[o], mk0);           astf(&smsk[o + 256], mk1);           astf(&smsk[o + 512], mk2);
    astf(&savg[o], mk0 * av0);     astf(&savg[o + 256], mk1 * av1);     astf(&savg[o + 512], mk2 * av2);
    astf(&sstd[o], mk0 * sqrtf(sq0 / fnum));
    astf(&sstd[o + 256], mk1 * sqrtf(sq1 / fnum));
    astf(&sstd[o + 512], mk2 * sqrtf(sq2 / fnum));
  }
  gbar(bar, 2);

  // ======================= Phase E: split-K partial combine (RTILE=14) ==========
  if (blk < NCOMB) {
    const float* savg = uT;
    int ea = blk / 168;
    int rem = blk - ea * 168;
    int it = rem / 12;
    int r2 = rem - it * 12;
    int dc = r2 >> 2;
    int jc = r2 & 3;
    int i0 = it * RTILE;
    int j0 = jc * JLEN;
    int d = (dc << 8) + t;
    for (int idx = t; idx < RTILE * JLEN; idx += 256) {
      int ii = idx / JLEN, j = idx - ii * JLEN;
      size_t o = ((size_t)(ea * LTOK + i0 + ii)) * LTOK + j0 + j;
      float l = ls[o];
      sh.cmb.lsr[ii][j] = l;
      sh.cmb.lnr[ii][j] = l * nz[o];
    }
    __syncthreads();
    float nm[RTILE], dn[RTILE];
#pragma unroll
    for (int ii = 0; ii < RTILE; ii++) { nm[ii] = 0.f; dn[ii] = 0.f; }
#pragma unroll 7
    for (int j = 0; j < JLEN; j++) {
      size_t b = ((size_t)(ea * LTOK + j0 + j)) * DDIM + d;
      float sd = aldf(&sstd[b]), sv = aldf(&savg[b]), sm = aldf(&smsk[b]);
#pragma unroll
      for (int ii = 0; ii < RTILE; ii++) {
        nm[ii] += sh.cmb.lnr[ii][j] * sd;
        nm[ii] += sh.cmb.lsr[ii][j] * sv;
        dn[ii] += sh.cmb.lsr[ii][j] * sm;
      }
    }
#pragma unroll
    for (int ii = 0; ii < RTILE; ii++) {
      size_t o = ((size_t)jc * NROWS + (ea * LTOK + i0 + ii)) * DDIM + d;
      astf(&numP[o], nm[ii]);
      astf(&denP[o], dn[ii]);
    }
  }
  gbar(bar, 3);

  // ======================= Phase F: reduce + inverse FFT + cls =======================
  {
    if (blk < NBATCH) {  // blocks 0,1 also copy the cls token row
      size_t b = (size_t)blk * (LTOK + 1) * DDIM;
      out[b + t] = x[b + t];
      out[b + t + 256] = x[b + t + 256];
      out[b + t + 512] = x[b + t + 512];
    }
    if (t < 128) {
      float sn, cs;
      __sincosf(2.0f * PI_F * (float)t / 256.0f, &sn, &cs);
      sh.fft.tw[t] = make_float2(cs, sn);
    }
    size_t rowz = ((size_t)a * LTOK + i) * DDIM;
#pragma unroll
    for (int e = 0; e < 3; e++) {
      int d = t + (e << 8);
      float num = 0.f, den = 0.f;
#pragma unroll
      for (int jc = 0; jc < JCH; jc++) {
        size_t o = (size_t)jc * NROWS * DDIM + rowz + d;
        num += aldf(&numP[o]);
        den += aldf(&denP[o]);
      }
      float mg = num / fmaxf(den, 1e-7f);
      int m = d / 3, r = d - 3 * m;          // decimate k = 3m + r
      int p = (r << 8) + (__brev((unsigned)m) >> 24);
      sh.fft.re[p] = mg * shph[e][t];        // phase from LDS carry (A2)
      sh.fft.im[p] = mg * shph[3 + e][t];
    }
    __syncthreads();
    fft_stages(sh.fft.re, sh.fft.im, sh.fft.tw, t);
    float a0r = sh.fft.re[t],       a0i = sh.fft.im[t];
    float a1r = sh.fft.re[256 + t], a1i = sh.fft.im[256 + t];
    float a2r = sh.fft.re[512 + t], a2i = sh.fft.im[512 + t];
    float sn, cs;
    __sincosf(2.0f * PI_F * (float)t / 768.0f, &sn, &cs);
    float2 w1 = make_float2(cs, sn);
    float2 w2 = make_float2(cs * cs - sn * sn, 2.f * cs * sn);
    float b1r = a1r * w1.x - a1i * w1.y, b1i = a1r * w1.y + a1i * w1.x;
    float b2r = a2r * w2.x - a2i * w2.y, b2i = a2r * w2.y + a2i * w2.x;
    float Xr[3];
    Xr[0] = a0r + b1r + b2r;
    Xr[1] = a0r + (-0.5f * b1r - S3 * b1i) + (-0.5f * b2r + S3 * b2i);
    Xr[2] = a0r + (-0.5f * b1r + S3 * b1i) + (-0.5f * b2r - S3 * b2i);
    size_t ob = ((size_t)a * (LTOK + 1) + 1 + i) * DDIM + t;
    const float inv = 1.0f / 768.0f;
    out[ob]       = Xr[0] * inv;
    out[ob + 256] = Xr[1] * inv;
    out[ob + 512] = Xr[2] * inv;
  }
}

// ---------------------------------------------------------------------------
extern "C" void kernel_launch(void* const* d_in, const int* in_sizes, int n_in,
                              void* d_out, int out_size, void* d_ws, size_t ws_size,
                              hipStream_t stream) {
  (void)in_sizes; (void)n_in; (void)out_size; (void)ws_size;
  const float* x    = (const float*)d_in[0];   // (2,197,768)
  const float* imgs = (const float*)d_in[1];   // (2,3,224,224)
  const float* ls   = (const float*)d_in[2];   // (2,196,196,1)
  const float* nz   = (const float*)d_in[3];   // (2,196,196,1)
  float* out = (float*)d_out;                  // (2,197,768)

  float* wf   = (float*)d_ws;
  float* uT   = wf;                       // 768 x 392 column-major; reused as s_avg
  float* sty  = wf + (size_t)NLD;
  float* sstd = wf + 4 * (size_t)NLD;     // offsets kept from round 8 layout
  float* smsk = wf + 5 * (size_t)NLD;
  float* numP = wf + 6 * (size_t)NLD;     // 4 x NLD
  float* denP = wf + 10 * (size_t)NLD;    // 4 x NLD
  u64* Mb = (u64*)(wf + 14 * (size_t)NLD);
  unsigned* bar = (unsigned*)(Mb + (size_t)NROWS * 4);  // 33 x 128-B lines

  hipMemsetAsync((void*)bar, 0, 33 * 128, stream);   // zero barrier tree + ctr

  mega<<<GRIDB, 256, 0, stream>>>(imgs, x, ls, nz, out,
                                  uT, sty, sstd, smsk,
                                  numP, denP, Mb, bar);
}